// Round 2
// baseline (733.775 us; speedup 1.0000x reference)
//
#include <hip/hip_runtime.h>
#include <hip/hip_bf16.h>

using bf16 = __hip_bfloat16;

#define BB   8
#define NN   12288
#define NTOK (BB*NN)      // 98304
#define NTK  3072
#define CC   256
#define CCO  512
#define HH   128
#define WWI  96
#define HWIN (HH*WWI)     // 12288
#define H2   64
#define W2   48
#define HW2  (H2*W2)      // 3072
#define RR   (BB*NTK)     // 24576

// ---- workspace layout (float-word offsets), total ~53 MB ----
#define O_CONV 0LL          // 6291456  (B*HW2*C)
#define O_NUM  6291456LL    // 6291456  (B*NT*C) merged skip+map numerator, then xd
#define O_CNT  12582912LL   // 98304
#define O_DEN  12681216LL   // 24576
#define O_ST1  12705792LL   // 512
#define O_AB1  12706304LL   // 512  (a1[256], bshift1[256])
#define O_WT   12706816LL   // 131072 (wT[c][o] = w[o][c]*a1[c])
#define O_B2   12837888LL   // 512
#define O_ST2  12838400LL   // 1024
#define O_AB2  12839424LL   // 1024
#define O_FLAG 12840448LL   // 4
#define O_META 12840452LL   // 4*98304 ints (int4 per token) — 16B-aligned
// end: 13233668 words = 52.9 MB

__device__ __forceinline__ float cvt(float v){ return v; }
__device__ __forceinline__ float cvt(bf16 v){ return __bfloat162float(v); }
template<typename T>
__device__ __forceinline__ float ld(const void* p, long long i){
    return cvt(((const T*)p)[i]);
}

// dtype detector: loc_orig ~ U(-1,1). If stored f32, first 64 f32 words are all
// in [-1,1]. If stored bf16, reinterpreted f32 words are huge/NaN. flag=1 -> bf16.
__global__ void k_flag(const float* __restrict__ locf, float* __restrict__ flag){
    if (threadIdx.x == 0){
        int bad = 0;
        for (int i = 0; i < 64; ++i){
            const float v = locf[i];
            if (!(v >= -1.0f && v <= 1.0f)) bad = 1;
        }
        flag[0] = bad ? 1.0f : 0.0f;
    }
}

__device__ __forceinline__ int2 gidx2(float lx, float ly, int h, int w){
    lx = fminf(fmaxf(lx, -1.f), 1.f);
    ly = fminf(fmaxf(ly, -1.f), 1.f);
    int xi = (int)rintf(0.5f*(lx+1.f)*(float)w - 0.5f);
    int yi = (int)rintf(0.5f*(ly+1.f)*(float)h - 0.5f);
    xi = min(max(xi,0), w-1); yi = min(max(yi,0), h-1);
    return make_int2(xi, yi);
}

// K1: per-token metadata (hw on 128x96, hw2 on 64x48, target token, weight)
//     + cnt and den accumulation.
template<typename T>
__device__ void meta_body(const void* loc, const int* __restrict__ iat, const void* wt,
                          int4* __restrict__ meta, float* __restrict__ cnt,
                          float* __restrict__ den){
    const int tok = blockIdx.x*256 + threadIdx.x;
    const int b = tok / NN;
    const float lx = ld<T>(loc, 2LL*tok);
    const float ly = ld<T>(loc, 2LL*tok + 1);
    const int2 g1 = gidx2(lx, ly, HH, WWI);
    const int2 g2 = gidx2(lx, ly, H2, W2);
    const int hw  = g1.x + g1.y*WWI;
    const int hw2 = g2.x + g2.y*W2;
    const int t = iat[tok];
    const float wv = ld<T>(wt, tok);
    int4 m; m.x = hw; m.y = hw2; m.z = t; m.w = __float_as_int(wv);
    meta[tok] = m;
    atomicAdd(&cnt[b*HWIN + hw], 1.0f);
    atomicAdd(&den[b*NTK + t], wv);
}
__global__ __launch_bounds__(256) void k_meta(
        const void* loc, const int* __restrict__ iat, const void* wt,
        const float* __restrict__ flag, int4* __restrict__ meta,
        float* __restrict__ cnt, float* __restrict__ den){
    if (flag[0] != 0.0f) meta_body<bf16>(loc, iat, wt, meta, cnt, den);
    else                 meta_body<float>(loc, iat, wt, meta, cnt, den);
}

// K2: gather x row once per token; scatter (a) skip numerator v*wv*sk into num,
//     (b) normalized conv contributions v/cnt * w[k] into the <=4 stride-2
//     output cells this map cell feeds (linearity of conv over normalized map).
template<typename T>
__device__ void scatter_body(const void* x, const void* dww, const void* skw,
                             const int4* __restrict__ meta, const float* __restrict__ cnt,
                             const int* __restrict__ ia,
                             float* __restrict__ conv, float* __restrict__ num){
    const int ch = threadIdx.x;
    float wreg[9];
    #pragma unroll
    for (int k = 0; k < 9; ++k) wreg[k] = ld<T>(dww, ch*9 + k);
    const float sk = ld<T>(skw, ch);
    const int base = blockIdx.x * 8;
    for (int k = 0; k < 8; ++k){
        const int tok = base + k;
        const int b = tok / NN;
        const int4 m = meta[tok];
        const int j = ia[tok];
        const float wv = __int_as_float(m.w);
        const float v = ld<T>(x, ((long long)(b*NN + j))*CC + ch);
        atomicAdd(&num[((long long)(b*NTK + m.z))*CC + ch], v*wv*sk);
        const int hw = m.x;
        const int ih = hw / WWI, iw = hw % WWI;
        const float vr = v / (cnt[b*HWIN + hw] + 1e-6f);
        int ohs[2], khs[2], nr = 0;
        if (ih & 1){
            ohs[nr] = (ih-1)>>1; khs[nr++] = 2;
            if (((ih+1)>>1) < H2){ ohs[nr] = (ih+1)>>1; khs[nr++] = 0; }
        } else { ohs[nr] = ih>>1; khs[nr++] = 1; }
        int ows[2], kws[2], nc = 0;
        if (iw & 1){
            ows[nc] = (iw-1)>>1; kws[nc++] = 2;
            if (((iw+1)>>1) < W2){ ows[nc] = (iw+1)>>1; kws[nc++] = 0; }
        } else { ows[nc] = iw>>1; kws[nc++] = 1; }
        for (int r = 0; r < nr; ++r)
            for (int c = 0; c < nc; ++c)
                atomicAdd(&conv[((long long)(b*HW2 + ohs[r]*W2 + ows[c]))*CC + ch],
                          vr * wreg[khs[r]*3 + kws[c]]);
    }
}
__global__ __launch_bounds__(256) void k_scatter(
        const void* x, const void* dww, const void* skw,
        const int4* __restrict__ meta, const float* __restrict__ cnt,
        const int* __restrict__ ia, const float* __restrict__ flag,
        float* __restrict__ conv, float* __restrict__ num){
    if (flag[0] != 0.0f) scatter_body<bf16>(x, dww, skw, meta, cnt, ia, conv, num);
    else                 scatter_body<float>(x, dww, skw, meta, cnt, ia, conv, num);
}

// K3: map2token — gather conv at token's 64x48 cell, weighted scatter into num.
__global__ __launch_bounds__(256) void k_m2t(
        const float* __restrict__ conv, const int4* __restrict__ meta,
        float* __restrict__ num){
    const int ch = threadIdx.x;
    const int base = blockIdx.x * 8;
    for (int k = 0; k < 8; ++k){
        const int tok = base + k;
        const int b = tok / NN;
        const int4 m = meta[tok];
        const float fv = conv[((long long)(b*HW2 + m.y))*CC + ch];
        atomicAdd(&num[((long long)(b*NTK + m.z))*CC + ch], fv*__int_as_float(m.w));
    }
}

// K4: xd = num/den (in place) + BN1 sum/sumsq.
__global__ __launch_bounds__(256) void k_combine(
        float* __restrict__ num, const float* __restrict__ den,
        float* __restrict__ st1){
    const int ch = threadIdx.x;
    const int r0 = blockIdx.x * 256;
    float s = 0.f, q = 0.f;
    for (int r = r0; r < r0 + 256; ++r){
        const float inv = 1.0f/(den[r] + 1e-6f);
        const long long i = (long long)r*CC + ch;
        const float xv = num[i]*inv;
        num[i] = xv;
        s += xv; q += xv*xv;
    }
    atomicAdd(&st1[ch], s);
    atomicAdd(&st1[CC + ch], q);
}

// K5: finalize BN1 (a1, bshift) and bias2[o] = sum_c bshift[c]*w[o,c].
template<typename T>
__device__ void bn1_body(const float* __restrict__ st1, const void* g1, const void* b1,
                         const void* cw, float* __restrict__ ab1, float* __restrict__ bias2){
    __shared__ float sb[CC];
    const int tid = threadIdx.x;
    if (tid < CC){
        const float mean = st1[tid]/(float)RR;
        const float var  = st1[CC + tid]/(float)RR - mean*mean;
        const float a  = ld<T>(g1, tid) * rsqrtf(var + 1e-5f);
        const float bb = ld<T>(b1, tid) - mean*a;
        ab1[tid] = a; ab1[CC + tid] = bb;
        sb[tid] = bb;
    }
    __syncthreads();
    float acc = 0.f;
    for (int c = 0; c < CC; ++c) acc += sb[c]*ld<T>(cw, (long long)tid*CC + c);
    bias2[tid] = acc;
}
__global__ __launch_bounds__(512) void k_bn1(
        const float* __restrict__ st1, const void* g1, const void* b1, const void* cw,
        const float* __restrict__ flag, float* __restrict__ ab1, float* __restrict__ bias2){
    if (flag[0] != 0.0f) bn1_body<bf16>(st1, g1, b1, cw, ab1, bias2);
    else                 bn1_body<float>(st1, g1, b1, cw, ab1, bias2);
}

// K5b: wT[c,o] = w[o,c]*a1[c]
template<typename T>
__device__ void wt_body(const void* cw, const float* __restrict__ ab1, float* __restrict__ wT){
    const int c = blockIdx.x, o = threadIdx.x;
    wT[(long long)c*CCO + o] = ld<T>(cw, (long long)o*CC + c) * ab1[c];
}
__global__ __launch_bounds__(512) void k_wt(
        const void* cw, const float* __restrict__ ab1,
        const float* __restrict__ flag, float* __restrict__ wT){
    if (flag[0] != 0.0f) wt_body<bf16>(cw, ab1, wT);
    else                 wt_body<float>(cw, ab1, wT);
}

// K6: y[r,o] = sum_c xd[r,c]*wT[c,o] + bias2[o] -> d_out (dtype per flag).
#define GR 32
__global__ __launch_bounds__(256) void k_gemm(
        const float* __restrict__ xd, const float* __restrict__ wT,
        const float* __restrict__ bias2, const float* __restrict__ flag,
        void* __restrict__ y){
    __shared__ float4 sx[GR*CC/4];          // 32 KB
    const int tid = threadIdx.x;
    const long long rowbase = (long long)blockIdx.x * GR;
    const float4* xd4 = (const float4*)(xd + rowbase*CC);
    for (int i = tid; i < GR*CC/4; i += 256) sx[i] = xd4[i];
    __syncthreads();
    float acc0[GR], acc1[GR];
    #pragma unroll
    for (int r = 0; r < GR; ++r){ acc0[r] = 0.f; acc1[r] = 0.f; }
    const int o0 = tid, o1 = tid + 256;
    for (int c4 = 0; c4 < CC/4; ++c4){
        const float* wp = wT + (long long)(4*c4)*CCO;
        const float wa0 = wp[o0],        wa1 = wp[o1];
        const float wb0 = wp[CCO+o0],    wb1 = wp[CCO+o1];
        const float wc0 = wp[2*CCO+o0],  wc1 = wp[2*CCO+o1];
        const float wd0 = wp[3*CCO+o0],  wd1 = wp[3*CCO+o1];
        #pragma unroll
        for (int r = 0; r < GR; ++r){
            const float4 xv = sx[r*(CC/4) + c4];
            acc0[r] += xv.x*wa0 + xv.y*wb0 + xv.z*wc0 + xv.w*wd0;
            acc1[r] += xv.x*wa1 + xv.y*wb1 + xv.z*wc1 + xv.w*wd1;
        }
    }
    const float bz0 = bias2[o0], bz1 = bias2[o1];
    if (flag[0] != 0.0f){
        bf16* yo = (bf16*)y;
        for (int r = 0; r < GR; ++r){
            yo[(rowbase + r)*CCO + o0] = __float2bfloat16(acc0[r] + bz0);
            yo[(rowbase + r)*CCO + o1] = __float2bfloat16(acc1[r] + bz1);
        }
    } else {
        float* yo = (float*)y;
        for (int r = 0; r < GR; ++r){
            yo[(rowbase + r)*CCO + o0] = acc0[r] + bz0;
            yo[(rowbase + r)*CCO + o1] = acc1[r] + bz1;
        }
    }
}

// K7: BN2 sum/sumsq over y (= d_out).
__global__ __launch_bounds__(512) void k_st2(
        const void* __restrict__ y, const float* __restrict__ flag,
        float* __restrict__ st2){
    const int o = threadIdx.x;
    const int r0 = blockIdx.x * 256;
    float s = 0.f, q = 0.f;
    if (flag[0] != 0.0f){
        const bf16* yp = (const bf16*)y;
        for (int r = r0; r < r0 + 256; ++r){
            const float v = __bfloat162float(yp[(long long)r*CCO + o]);
            s += v; q += v*v;
        }
    } else {
        const float* yp = (const float*)y;
        for (int r = r0; r < r0 + 256; ++r){
            const float v = yp[(long long)r*CCO + o];
            s += v; q += v*v;
        }
    }
    atomicAdd(&st2[o], s);
    atomicAdd(&st2[CCO + o], q);
}

// K7b: finalize BN2 scale/shift.
template<typename T>
__device__ void bn2_body(const float* __restrict__ st2, const void* g2, const void* b2,
                         float* __restrict__ ab2){
    const int tid = threadIdx.x;
    const float mean = st2[tid]/(float)RR;
    const float var  = st2[CCO + tid]/(float)RR - mean*mean;
    const float a = ld<T>(g2, tid) * rsqrtf(var + 1e-5f);
    ab2[tid] = a;
    ab2[CCO + tid] = ld<T>(b2, tid) - mean*a;
}
__global__ __launch_bounds__(512) void k_bn2(
        const float* __restrict__ st2, const void* g2, const void* b2,
        const float* __restrict__ flag, float* __restrict__ ab2){
    if (flag[0] != 0.0f) bn2_body<bf16>(st2, g2, b2, ab2);
    else                 bn2_body<float>(st2, g2, b2, ab2);
}

// K8: in-place on d_out: out = relu(y*a2 + b2)
__global__ __launch_bounds__(256) void k_out(
        void* __restrict__ y, const float* __restrict__ ab2,
        const float* __restrict__ flag){
    const long long i = (long long)blockIdx.x*256 + threadIdx.x;
    const int o = (int)(i & (CCO-1));
    if (flag[0] != 0.0f){
        bf16* p = (bf16*)y;
        float v = __bfloat162float(p[i]);
        v = v*ab2[o] + ab2[CCO + o];
        p[i] = __float2bfloat16(fmaxf(v, 0.f));
    } else {
        float* p = (float*)y;
        float v = p[i]*ab2[o] + ab2[CCO + o];
        p[i] = fmaxf(v, 0.f);
    }
}

extern "C" void kernel_launch(void* const* d_in, const int* in_sizes, int n_in,
                              void* d_out, int out_size, void* d_ws, size_t ws_size,
                              hipStream_t stream){
    (void)in_sizes; (void)n_in; (void)out_size; (void)ws_size;
    const void* x   = d_in[0];
    const void* loc = d_in[1];
    const int*  ia  = (const int*)d_in[2];
    // d_in[3] agg_weight: unused by reference
    const int*  iat = (const int*)d_in[5];
    const void* wt  = d_in[6];
    // d_in[7]=H, d_in[8]=W fixed 128,96
    const void* dww = d_in[9];
    const void* skw = d_in[10];
    const void* g1  = d_in[11];
    const void* b1  = d_in[12];
    const void* cw  = d_in[13];
    const void* g2  = d_in[14];
    const void* b2  = d_in[15];
    float* ws = (float*)d_ws;
    float* flag = ws + O_FLAG;

    // zero: conv, num, cnt, den, st1 (contiguous) + st2
    hipMemsetAsync(ws, 0, (size_t)(O_ST1 + 512)*4, stream);
    hipMemsetAsync(ws + O_ST2, 0, (size_t)1024*4, stream);

    k_flag<<<dim3(1), dim3(64), 0, stream>>>((const float*)loc, flag);

    k_meta<<<dim3(NTOK/256), dim3(256), 0, stream>>>(
        loc, iat, wt, flag, (int4*)(ws + O_META), ws + O_CNT, ws + O_DEN);

    k_scatter<<<dim3(NTOK/8), dim3(256), 0, stream>>>(
        x, dww, skw, (const int4*)(ws + O_META), ws + O_CNT, ia, flag,
        ws + O_CONV, ws + O_NUM);

    k_m2t<<<dim3(NTOK/8), dim3(256), 0, stream>>>(
        ws + O_CONV, (const int4*)(ws + O_META), ws + O_NUM);

    k_combine<<<dim3(RR/256), dim3(256), 0, stream>>>(
        ws + O_NUM, ws + O_DEN, ws + O_ST1);

    k_bn1<<<dim3(1), dim3(512), 0, stream>>>(
        ws + O_ST1, g1, b1, cw, flag, ws + O_AB1, ws + O_B2);

    k_wt<<<dim3(CC), dim3(512), 0, stream>>>(cw, ws + O_AB1, flag, ws + O_WT);

    k_gemm<<<dim3(RR/GR), dim3(256), 0, stream>>>(
        ws + O_NUM, ws + O_WT, ws + O_B2, flag, d_out);

    k_st2<<<dim3(RR/256), dim3(512), 0, stream>>>(d_out, flag, ws + O_ST2);

    k_bn2<<<dim3(1), dim3(512), 0, stream>>>(ws + O_ST2, g2, b2, flag, ws + O_AB2);

    k_out<<<dim3((RR*CCO)/256), dim3(256), 0, stream>>>(d_out, ws + O_AB2, flag);
}

// Round 3
// 604.025 us; speedup vs baseline: 1.2148x; 1.2148x over previous
//
#include <hip/hip_runtime.h>
#include <hip/hip_bf16.h>

using bf16 = __hip_bfloat16;

#define BB   8
#define NN   12288
#define NTOK (BB*NN)      // 98304
#define NTK  3072
#define CC   256
#define CCO  512
#define HH   128
#define WWI  96
#define HWIN (HH*WWI)     // 12288
#define H2   64
#define W2   48
#define HW2  (H2*W2)      // 3072
#define RR   (BB*NTK)     // 24576

// ---- workspace layout (float-word offsets), end = 13233668 words = 52.93 MB
// (exactly the footprint proven to fit in round 2)
#define O_CONV  0LL          // 6291456  (B*HW2*C) f32
#define O_XD    6291456LL    // 6291456  (B*NT*C) f32
#define O_WT    12582912LL   // 131072   wT[c][o] = w[o][c]*a1[c]
#define O_ST1   12713984LL   // 512
#define O_ST2   12714496LL   // 1024   (contiguous with ST1 for one memset)
#define O_AB1   12715520LL   // 512
#define O_B2    12716032LL   // 512
#define O_AB2   12716544LL   // 1024
#define O_FLAG  12717568LL   // 4
#define O_META  12717572LL   // 196608  int2 per token {hw2, wv bits} (8B aligned)
#define O_OFFA  12914180LL   // 98304   ints (hist -> excl scan -> incl after fill)
#define O_OFFB  13012484LL   // 24576   ints
#define O_LISTA 13037060LL   // 98304   ints: gathered x-row index (b*NN+ia[tok])
#define O_LISTB 13135364LL   // 98304   ints: token id
// end 13233668

__device__ __forceinline__ float cvt(float v){ return v; }
__device__ __forceinline__ float cvt(bf16 v){ return __bfloat162float(v); }
template<typename T>
__device__ __forceinline__ float ld(const void* p, long long i){
    return cvt(((const T*)p)[i]);
}

// dtype detector: loc_orig ~ U(-1,1); f32 words all in [-1,1], bf16-reinterp huge.
__global__ void k_flag(const float* __restrict__ locf, float* __restrict__ flag){
    if (threadIdx.x == 0){
        int bad = 0;
        for (int i = 0; i < 64; ++i){
            const float v = locf[i];
            if (!(v >= -1.0f && v <= 1.0f)) bad = 1;
        }
        flag[0] = bad ? 1.0f : 0.0f;
    }
}

__device__ __forceinline__ int2 gidx2(float lx, float ly, int h, int w){
    lx = fminf(fmaxf(lx, -1.f), 1.f);
    ly = fminf(fmaxf(ly, -1.f), 1.f);
    int xi = (int)rintf(0.5f*(lx+1.f)*(float)w - 0.5f);
    int yi = (int)rintf(0.5f*(ly+1.f)*(float)h - 0.5f);
    xi = min(max(xi,0), w-1); yi = min(max(yi,0), h-1);
    return make_int2(xi, yi);
}

// K1: meta {hw2, wv} + histograms into offA (cells) and offB (targets).
template<typename T>
__device__ void meta_body(const void* loc, const int* __restrict__ iat, const void* wt,
                          int2* __restrict__ meta, int* __restrict__ offA,
                          int* __restrict__ offB){
    const int tok = blockIdx.x*256 + threadIdx.x;
    const int b = tok / NN;
    const float lx = ld<T>(loc, 2LL*tok);
    const float ly = ld<T>(loc, 2LL*tok + 1);
    const int2 g1 = gidx2(lx, ly, HH, WWI);
    const int2 g2 = gidx2(lx, ly, H2, W2);
    const float wv = ld<T>(wt, tok);
    int2 m; m.x = g2.x + g2.y*W2; m.y = __float_as_int(wv);
    meta[tok] = m;
    atomicAdd(&offA[b*HWIN + g1.x + g1.y*WWI], 1);
    atomicAdd(&offB[b*NTK + iat[tok]], 1);
}
__global__ __launch_bounds__(256) void k_meta(
        const void* loc, const int* __restrict__ iat, const void* wt,
        const float* __restrict__ flag, int2* __restrict__ meta,
        int* __restrict__ offA, int* __restrict__ offB){
    if (flag[0] != 0.0f) meta_body<bf16>(loc, iat, wt, meta, offA, offB);
    else                 meta_body<float>(loc, iat, wt, meta, offA, offB);
}

// K2: single-block exclusive scans (in place) of offA then offB.
__device__ void scan_block(int* a, int n){
    __shared__ int part[1024];
    const int tid = threadIdx.x;
    const int chunk = n / 1024;
    const int base = tid * chunk;
    int s = 0;
    for (int i = 0; i < chunk; ++i) s += a[base+i];
    part[tid] = s;
    __syncthreads();
    for (int d = 1; d < 1024; d <<= 1){
        const int v = (tid >= d) ? part[tid-d] : 0;
        __syncthreads();
        part[tid] += v;
        __syncthreads();
    }
    int run = (tid == 0) ? 0 : part[tid-1];
    for (int i = 0; i < chunk; ++i){
        const int v = a[base+i];
        a[base+i] = run;
        run += v;
    }
}
__global__ __launch_bounds__(1024) void k_scan(int* offA, int* offB){
    scan_block(offA, NTOK);
    __syncthreads();
    scan_block(offB, RR);
}

// K3: fill both CSR lists. After this, offA/offB hold INCLUSIVE scans
//     (start of row g = off[g-1], end = off[g]).
template<typename T>
__device__ void fill_body(const void* loc, const int* __restrict__ ia,
                          const int* __restrict__ iat,
                          int* __restrict__ offA, int* __restrict__ offB,
                          int* __restrict__ listA, int* __restrict__ listB){
    const int tok = blockIdx.x*256 + threadIdx.x;
    const int b = tok / NN;
    const float lx = ld<T>(loc, 2LL*tok);
    const float ly = ld<T>(loc, 2LL*tok + 1);
    const int2 g1 = gidx2(lx, ly, HH, WWI);
    const int pa = atomicAdd(&offA[b*HWIN + g1.x + g1.y*WWI], 1);
    listA[pa] = b*NN + ia[tok];
    const int pb = atomicAdd(&offB[b*NTK + iat[tok]], 1);
    listB[pb] = tok;
}
__global__ __launch_bounds__(256) void k_fill(
        const void* loc, const int* __restrict__ ia, const int* __restrict__ iat,
        const float* __restrict__ flag,
        int* __restrict__ offA, int* __restrict__ offB,
        int* __restrict__ listA, int* __restrict__ listB){
    if (flag[0] != 0.0f) fill_body<bf16>(loc, ia, iat, offA, offB, listA, listB);
    else                 fill_body<float>(loc, ia, iat, offA, offB, listA, listB);
}

// K4: gather-conv. One block per (b, output cell), thread = channel.
//     in[cell] = (sum of x rows in cell)/(len+1e-6); out = 3x3 stride-2 conv.
template<typename T>
__device__ void conv_body(const void* x, const void* dww,
                          const int* __restrict__ offA, const int* __restrict__ listA,
                          float* __restrict__ conv){
    const int ch = threadIdx.x;
    const int b = blockIdx.x / HW2;
    const int p = blockIdx.x % HW2;
    const int oh = p / W2, ow = p % W2;
    __shared__ int s_start[9], s_len[9];
    if (ch < 9){
        const int kh = ch/3, kw = ch%3;
        const int ih = 2*oh - 1 + kh, iw = 2*ow - 1 + kw;
        int st = 0, ln = 0;
        if (ih >= 0 && ih < HH && iw >= 0 && iw < WWI){
            const int g = b*HWIN + ih*WWI + iw;
            const int e = offA[g];
            const int s0 = (g > 0) ? offA[g-1] : 0;
            st = s0; ln = e - s0;
        }
        s_start[ch] = st; s_len[ch] = ln;
    }
    __syncthreads();
    float acc = 0.f;
    #pragma unroll
    for (int k = 0; k < 9; ++k){
        const int ln = s_len[k];
        if (ln == 0) continue;
        const int st = s_start[k];
        float sum = 0.f;
        for (int i = 0; i < ln; ++i){
            const int row = listA[st+i];                 // broadcast
            sum += ld<T>(x, (long long)row*CC + ch);     // coalesced row
        }
        acc += ld<T>(dww, ch*9 + k) * (sum / ((float)ln + 1e-6f));
    }
    conv[(long long)blockIdx.x*CC + ch] = acc;
}
__global__ __launch_bounds__(256) void k_conv(
        const void* x, const void* dww, const float* __restrict__ flag,
        const int* __restrict__ offA, const int* __restrict__ listA,
        float* __restrict__ conv){
    if (flag[0] != 0.0f) conv_body<bf16>(x, dww, offA, listA, conv);
    else                 conv_body<float>(x, dww, offA, listA, conv);
}

// K5: per-target gather: xd = (sum wv*(sk*x + conv[hw2]))/(sum wv + 1e-6)
//     + BN1 partial stats. TGT targets per block, thread = channel.
#define TGT 32
template<typename T>
__device__ void num_body(const void* x, const float* __restrict__ conv,
                         const void* skw, const int* __restrict__ ia,
                         const int2* __restrict__ meta,
                         const int* __restrict__ offB, const int* __restrict__ listB,
                         float* __restrict__ xd, float* __restrict__ st1){
    const int ch = threadIdx.x;
    const float sk = ld<T>(skw, ch);
    const int b = (blockIdx.x * TGT) / NTK;
    float s = 0.f, q = 0.f;
    for (int r = 0; r < TGT; ++r){
        const int gt = blockIdx.x*TGT + r;
        const int e  = offB[gt];
        const int st = (gt > 0) ? offB[gt-1] : 0;
        float acc = 0.f, den = 0.f;
        for (int i = st; i < e; ++i){
            const int tok = listB[i];                    // broadcast
            const int2 m = meta[tok];                    // broadcast
            const float wv = __int_as_float(m.y);
            const int j = ia[tok];                       // broadcast
            const float xv = ld<T>(x, ((long long)(b*NN + j))*CC + ch);
            const float cv = conv[((long long)(b*HW2 + m.x))*CC + ch];
            acc += wv*(sk*xv + cv);
            den += wv;
        }
        const float v = acc / (den + 1e-6f);
        xd[(long long)gt*CC + ch] = v;
        s += v; q += v*v;
    }
    atomicAdd(&st1[ch], s);
    atomicAdd(&st1[CC + ch], q);
}
__global__ __launch_bounds__(256) void k_num(
        const void* x, const float* __restrict__ conv, const void* skw,
        const int* __restrict__ ia, const int2* __restrict__ meta,
        const int* __restrict__ offB, const int* __restrict__ listB,
        const float* __restrict__ flag,
        float* __restrict__ xd, float* __restrict__ st1){
    if (flag[0] != 0.0f) num_body<bf16>(x, conv, skw, ia, meta, offB, listB, xd, st1);
    else                 num_body<float>(x, conv, skw, ia, meta, offB, listB, xd, st1);
}

// K6: finalize BN1 (a1, bshift) and bias2[o] = sum_c bshift[c]*w[o,c].
template<typename T>
__device__ void bn1_body(const float* __restrict__ st1, const void* g1, const void* b1,
                         const void* cw, float* __restrict__ ab1, float* __restrict__ bias2){
    __shared__ float sb[CC];
    const int tid = threadIdx.x;
    if (tid < CC){
        const float mean = st1[tid]/(float)RR;
        const float var  = st1[CC + tid]/(float)RR - mean*mean;
        const float a  = ld<T>(g1, tid) * rsqrtf(var + 1e-5f);
        const float bb = ld<T>(b1, tid) - mean*a;
        ab1[tid] = a; ab1[CC + tid] = bb;
        sb[tid] = bb;
    }
    __syncthreads();
    float acc = 0.f;
    for (int c = 0; c < CC; ++c) acc += sb[c]*ld<T>(cw, (long long)tid*CC + c);
    bias2[tid] = acc;
}
__global__ __launch_bounds__(512) void k_bn1(
        const float* __restrict__ st1, const void* g1, const void* b1, const void* cw,
        const float* __restrict__ flag, float* __restrict__ ab1, float* __restrict__ bias2){
    if (flag[0] != 0.0f) bn1_body<bf16>(st1, g1, b1, cw, ab1, bias2);
    else                 bn1_body<float>(st1, g1, b1, cw, ab1, bias2);
}

// K6b: wT[c,o] = w[o,c]*a1[c]
template<typename T>
__device__ void wt_body(const void* cw, const float* __restrict__ ab1, float* __restrict__ wT){
    const int c = blockIdx.x, o = threadIdx.x;
    wT[(long long)c*CCO + o] = ld<T>(cw, (long long)o*CC + c) * ab1[c];
}
__global__ __launch_bounds__(512) void k_wt(
        const void* cw, const float* __restrict__ ab1,
        const float* __restrict__ flag, float* __restrict__ wT){
    if (flag[0] != 0.0f) wt_body<bf16>(cw, ab1, wT);
    else                 wt_body<float>(cw, ab1, wT);
}

// K7: GEMM y[r,o] = xd[r,:]·wT[:,o] + bias2[o] -> d_out, + fused BN2 partials.
#define GR 32
__global__ __launch_bounds__(256) void k_gemm(
        const float* __restrict__ xd, const float* __restrict__ wT,
        const float* __restrict__ bias2, const float* __restrict__ flag,
        void* __restrict__ y, float* __restrict__ st2){
    __shared__ float4 sx[GR*CC/4];          // 32 KB
    const int tid = threadIdx.x;
    const long long rowbase = (long long)blockIdx.x * GR;
    const float4* xd4 = (const float4*)(xd + rowbase*CC);
    for (int i = tid; i < GR*CC/4; i += 256) sx[i] = xd4[i];
    __syncthreads();
    float acc0[GR], acc1[GR];
    #pragma unroll
    for (int r = 0; r < GR; ++r){ acc0[r] = 0.f; acc1[r] = 0.f; }
    const int o0 = tid, o1 = tid + 256;
    for (int c4 = 0; c4 < CC/4; ++c4){
        const float* wp = wT + (long long)(4*c4)*CCO;
        const float wa0 = wp[o0],        wa1 = wp[o1];
        const float wb0 = wp[CCO+o0],    wb1 = wp[CCO+o1];
        const float wc0 = wp[2*CCO+o0],  wc1 = wp[2*CCO+o1];
        const float wd0 = wp[3*CCO+o0],  wd1 = wp[3*CCO+o1];
        #pragma unroll
        for (int r = 0; r < GR; ++r){
            const float4 xv = sx[r*(CC/4) + c4];
            acc0[r] += xv.x*wa0 + xv.y*wb0 + xv.z*wc0 + xv.w*wd0;
            acc1[r] += xv.x*wa1 + xv.y*wb1 + xv.z*wc1 + xv.w*wd1;
        }
    }
    const float bz0 = bias2[o0], bz1 = bias2[o1];
    float s0 = 0.f, q0 = 0.f, s1 = 0.f, q1 = 0.f;
    #pragma unroll
    for (int r = 0; r < GR; ++r){
        acc0[r] += bz0; acc1[r] += bz1;
        s0 += acc0[r]; q0 += acc0[r]*acc0[r];
        s1 += acc1[r]; q1 += acc1[r]*acc1[r];
    }
    if (flag[0] != 0.0f){
        bf16* yo = (bf16*)y;
        for (int r = 0; r < GR; ++r){
            yo[(rowbase + r)*CCO + o0] = __float2bfloat16(acc0[r]);
            yo[(rowbase + r)*CCO + o1] = __float2bfloat16(acc1[r]);
        }
    } else {
        float* yo = (float*)y;
        for (int r = 0; r < GR; ++r){
            yo[(rowbase + r)*CCO + o0] = acc0[r];
            yo[(rowbase + r)*CCO + o1] = acc1[r];
        }
    }
    atomicAdd(&st2[o0], s0);
    atomicAdd(&st2[CCO + o0], q0);
    atomicAdd(&st2[o1], s1);
    atomicAdd(&st2[CCO + o1], q1);
}

// K8: finalize BN2 scale/shift.
template<typename T>
__device__ void bn2_body(const float* __restrict__ st2, const void* g2, const void* b2,
                         float* __restrict__ ab2){
    const int tid = threadIdx.x;
    const float mean = st2[tid]/(float)RR;
    const float var  = st2[CCO + tid]/(float)RR - mean*mean;
    const float a = ld<T>(g2, tid) * rsqrtf(var + 1e-5f);
    ab2[tid] = a;
    ab2[CCO + tid] = ld<T>(b2, tid) - mean*a;
}
__global__ __launch_bounds__(512) void k_bn2(
        const float* __restrict__ st2, const void* g2, const void* b2,
        const float* __restrict__ flag, float* __restrict__ ab2){
    if (flag[0] != 0.0f) bn2_body<bf16>(st2, g2, b2, ab2);
    else                 bn2_body<float>(st2, g2, b2, ab2);
}

// K9: in-place on d_out: out = relu(y*a2 + b2)
__global__ __launch_bounds__(256) void k_out(
        void* __restrict__ y, const float* __restrict__ ab2,
        const float* __restrict__ flag){
    const long long i = (long long)blockIdx.x*256 + threadIdx.x;
    const int o = (int)(i & (CCO-1));
    if (flag[0] != 0.0f){
        bf16* p = (bf16*)y;
        float v = __bfloat162float(p[i]);
        v = v*ab2[o] + ab2[CCO + o];
        p[i] = __float2bfloat16(fmaxf(v, 0.f));
    } else {
        float* p = (float*)y;
        float v = p[i]*ab2[o] + ab2[CCO + o];
        p[i] = fmaxf(v, 0.f);
    }
}

extern "C" void kernel_launch(void* const* d_in, const int* in_sizes, int n_in,
                              void* d_out, int out_size, void* d_ws, size_t ws_size,
                              hipStream_t stream){
    (void)in_sizes; (void)n_in; (void)out_size; (void)ws_size;
    const void* x   = d_in[0];
    const void* loc = d_in[1];
    const int*  ia  = (const int*)d_in[2];
    // d_in[3] agg_weight: unused by reference
    const int*  iat = (const int*)d_in[5];
    const void* wt  = d_in[6];
    // d_in[7]=H, d_in[8]=W fixed 128,96
    const void* dww = d_in[9];
    const void* skw = d_in[10];
    const void* g1  = d_in[11];
    const void* b1  = d_in[12];
    const void* cw  = d_in[13];
    const void* g2  = d_in[14];
    const void* b2  = d_in[15];
    float* ws = (float*)d_ws;
    float* flag = ws + O_FLAG;
    int* offA  = (int*)(ws + O_OFFA);
    int* offB  = (int*)(ws + O_OFFB);
    int* listA = (int*)(ws + O_LISTA);
    int* listB = (int*)(ws + O_LISTB);
    int2* meta = (int2*)(ws + O_META);

    // zero: st1+st2 (contiguous 1536 words) and offA+offB (contiguous 122880)
    hipMemsetAsync(ws + O_ST1,  0, (size_t)1536*4, stream);
    hipMemsetAsync(ws + O_OFFA, 0, (size_t)(98304 + 24576)*4, stream);

    k_flag<<<dim3(1), dim3(64), 0, stream>>>((const float*)loc, flag);

    k_meta<<<dim3(NTOK/256), dim3(256), 0, stream>>>(
        loc, iat, wt, flag, meta, offA, offB);

    k_scan<<<dim3(1), dim3(1024), 0, stream>>>(offA, offB);

    k_fill<<<dim3(NTOK/256), dim3(256), 0, stream>>>(
        loc, ia, iat, flag, offA, offB, listA, listB);

    k_conv<<<dim3(BB*HW2), dim3(256), 0, stream>>>(
        x, dww, flag, offA, listA, ws + O_CONV);

    k_num<<<dim3(RR/TGT), dim3(256), 0, stream>>>(
        x, ws + O_CONV, skw, ia, meta, offB, listB, flag, ws + O_XD, ws + O_ST1);

    k_bn1<<<dim3(1), dim3(512), 0, stream>>>(
        ws + O_ST1, g1, b1, cw, flag, ws + O_AB1, ws + O_B2);

    k_wt<<<dim3(CC), dim3(512), 0, stream>>>(cw, ws + O_AB1, flag, ws + O_WT);

    k_gemm<<<dim3(RR/GR), dim3(256), 0, stream>>>(
        ws + O_XD, ws + O_WT, ws + O_B2, flag, d_out, ws + O_ST2);

    k_bn2<<<dim3(1), dim3(512), 0, stream>>>(ws + O_ST2, g2, b2, flag, ws + O_AB2);

    k_out<<<dim3((RR*CCO)/256), dim3(256), 0, stream>>>(d_out, ws + O_AB2, flag);
}

// Round 5
// 474.515 us; speedup vs baseline: 1.5464x; 1.2729x over previous
//
#include <hip/hip_runtime.h>
#include <hip/hip_bf16.h>

using bf16 = __hip_bfloat16;
typedef __attribute__((ext_vector_type(8))) short bf16x8;
typedef __attribute__((ext_vector_type(4))) float f32x4;

#define BB   8
#define NN   12288
#define NTOK (BB*NN)      // 98304
#define NTK  3072
#define CC   256
#define CCO  512
#define HH   128
#define WWI  96
#define HWIN (HH*WWI)     // 12288
#define H2   64
#define W2   48
#define HW2  (H2*W2)      // 3072
#define RR   (BB*NTK)     // 24576

// ---- workspace layout (float-word offsets), end = 13233668 words = 52.93 MB
#define O_CONV  0LL          // conv bf16: 6291456 elems -> 3145728 words
#define O_XD    6291456LL    // xdf bf16 fragment layout: 6291456 elems -> 3145728 words
#define O_AUX   9437184LL    // 128 ints (scan block sums)
#define O_WT    12582912LL   // wTf bf16 fragment layout: 131072 elems -> 65536 words
#define O_ST1   12713984LL   // 512
#define O_ST2   12714496LL   // 1024 (contiguous with ST1)
#define O_AB1   12715520LL   // 512
#define O_B2    12716032LL   // 512
#define O_AB2   12716544LL   // 1024
#define O_FLAG  12717568LL   // 4
#define O_META  12717572LL   // 196608 (int2 per token {hw2, wv})
#define O_OFF   12914180LL   // 122880 ints: joint [cells(98304) | targets(24576)]
#define O_LIST  13037060LL   // 196608 ints: joint [listA | listB]
// end 13233668

__device__ __forceinline__ float cvt(float v){ return v; }
__device__ __forceinline__ float cvt(bf16 v){ return __bfloat162float(v); }
template<typename T>
__device__ __forceinline__ float ld(const void* p, long long i){
    return cvt(((const T*)p)[i]);
}

// dtype detector: loc_orig ~ U(-1,1); f32 words all in [-1,1], bf16-reinterp huge.
__global__ void k_flag(const float* __restrict__ locf, float* __restrict__ flag){
    if (threadIdx.x == 0){
        int bad = 0;
        for (int i = 0; i < 64; ++i){
            const float v = locf[i];
            if (!(v >= -1.0f && v <= 1.0f)) bad = 1;
        }
        flag[0] = bad ? 1.0f : 0.0f;
    }
}

__device__ __forceinline__ int2 gidx2(float lx, float ly, int h, int w){
    lx = fminf(fmaxf(lx, -1.f), 1.f);
    ly = fminf(fmaxf(ly, -1.f), 1.f);
    int xi = (int)rintf(0.5f*(lx+1.f)*(float)w - 0.5f);
    int yi = (int)rintf(0.5f*(ly+1.f)*(float)h - 0.5f);
    xi = min(max(xi,0), w-1); yi = min(max(yi,0), h-1);
    return make_int2(xi, yi);
}

// K1: meta {hw2, wv} + joint histogram (cells then targets).
template<typename T>
__device__ void meta_body(const void* loc, const int* __restrict__ iat, const void* wt,
                          int2* __restrict__ meta, int* __restrict__ off){
    const int tok = blockIdx.x*256 + threadIdx.x;
    const int b = tok / NN;
    const float lx = ld<T>(loc, 2LL*tok);
    const float ly = ld<T>(loc, 2LL*tok + 1);
    const int2 g1 = gidx2(lx, ly, HH, WWI);
    const int2 g2 = gidx2(lx, ly, H2, W2);
    const float wv = ld<T>(wt, tok);
    int2 m; m.x = g2.x + g2.y*W2; m.y = __float_as_int(wv);
    meta[tok] = m;
    atomicAdd(&off[b*HWIN + g1.x + g1.y*WWI], 1);
    atomicAdd(&off[NTOK + b*NTK + iat[tok]], 1);
}
__global__ __launch_bounds__(256) void k_meta(
        const void* loc, const int* __restrict__ iat, const void* wt,
        const float* __restrict__ flag, int2* __restrict__ meta,
        int* __restrict__ off){
    if (flag[0] != 0.0f) meta_body<bf16>(loc, iat, wt, meta, off);
    else                 meta_body<float>(loc, iat, wt, meta, off);
}

// Scan over joint off[122880]: S1 per-block excl scan + totals, S2 scan totals, S3 add.
#define SCN  (NTOK + RR)     // 122880
#define SCB  120             // 120 blocks x 1024
__global__ __launch_bounds__(1024) void k_scan1(int* __restrict__ off, int* __restrict__ aux){
    __shared__ int sm[1024];
    const int tid = threadIdx.x;
    const int gid = blockIdx.x*1024 + tid;
    const int v = off[gid];
    sm[tid] = v;
    __syncthreads();
    for (int d = 1; d < 1024; d <<= 1){
        const int t = (tid >= d) ? sm[tid-d] : 0;
        __syncthreads();
        sm[tid] += t;
        __syncthreads();
    }
    off[gid] = sm[tid] - v;                    // exclusive within block
    if (tid == 1023) aux[blockIdx.x] = sm[1023];
}
__global__ __launch_bounds__(128) void k_scan2(int* __restrict__ aux){
    __shared__ int sm[128];
    const int tid = threadIdx.x;
    const int v = (tid < SCB) ? aux[tid] : 0;
    sm[tid] = v;
    __syncthreads();
    for (int d = 1; d < 128; d <<= 1){
        const int t = (tid >= d) ? sm[tid-d] : 0;
        __syncthreads();
        sm[tid] += t;
        __syncthreads();
    }
    if (tid < SCB) aux[tid] = sm[tid] - v;     // exclusive
}
__global__ __launch_bounds__(1024) void k_scan3(int* __restrict__ off, const int* __restrict__ aux){
    off[blockIdx.x*1024 + threadIdx.x] += aux[blockIdx.x];
}

// K3: fill joint CSR list. After this off holds inclusive ends.
template<typename T>
__device__ void fill_body(const void* loc, const int* __restrict__ ia,
                          const int* __restrict__ iat,
                          int* __restrict__ off, int* __restrict__ list){
    const int tok = blockIdx.x*256 + threadIdx.x;
    const int b = tok / NN;
    const float lx = ld<T>(loc, 2LL*tok);
    const float ly = ld<T>(loc, 2LL*tok + 1);
    const int2 g1 = gidx2(lx, ly, HH, WWI);
    const int pa = atomicAdd(&off[b*HWIN + g1.x + g1.y*WWI], 1);
    list[pa] = b*NN + ia[tok];
    const int pb = atomicAdd(&off[NTOK + b*NTK + iat[tok]], 1);
    list[pb] = tok;
}
__global__ __launch_bounds__(256) void k_fill(
        const void* loc, const int* __restrict__ ia, const int* __restrict__ iat,
        const float* __restrict__ flag,
        int* __restrict__ off, int* __restrict__ list){
    if (flag[0] != 0.0f) fill_body<bf16>(loc, ia, iat, off, list);
    else                 fill_body<float>(loc, ia, iat, off, list);
}

// K4: gather-conv -> bf16. One block per (b, out cell), thread = channel.
template<typename T>
__device__ void conv_body(const void* x, const void* dww,
                          const int* __restrict__ off, const int* __restrict__ list,
                          bf16* __restrict__ conv){
    const int ch = threadIdx.x;
    const int b = blockIdx.x / HW2;
    const int p = blockIdx.x % HW2;
    const int oh = p / W2, ow = p % W2;
    __shared__ int s_start[9], s_len[9];
    if (ch < 9){
        const int kh = ch/3, kw = ch%3;
        const int ih = 2*oh - 1 + kh, iw = 2*ow - 1 + kw;
        int st = 0, ln = 0;
        if (ih >= 0 && ih < HH && iw >= 0 && iw < WWI){
            const int g = b*HWIN + ih*WWI + iw;
            const int e = off[g];
            const int s0 = (g > 0) ? off[g-1] : 0;
            st = s0; ln = e - s0;
        }
        s_start[ch] = st; s_len[ch] = ln;
    }
    __syncthreads();
    float acc = 0.f;
    #pragma unroll
    for (int k = 0; k < 9; ++k){
        const int ln = s_len[k];
        if (ln == 0) continue;
        const int st = s_start[k];
        float sum = 0.f;
        for (int i = 0; i < ln; ++i){
            const int row = list[st+i];                  // broadcast
            sum += ld<T>(x, (long long)row*CC + ch);     // coalesced row
        }
        acc += ld<T>(dww, ch*9 + k) * (sum / ((float)ln + 1e-6f));
    }
    conv[(long long)blockIdx.x*CC + ch] = __float2bfloat16(acc);
}
__global__ __launch_bounds__(256) void k_conv(
        const void* x, const void* dww, const float* __restrict__ flag,
        const int* __restrict__ off, const int* __restrict__ list,
        bf16* __restrict__ conv){
    if (flag[0] != 0.0f) conv_body<bf16>(x, dww, off, list, conv);
    else                 conv_body<float>(x, dww, off, list, conv);
}

// K5: per-target gather -> xd in MFMA-A fragment layout (bf16) + BN1 stats.
//     xdf[mt*4096 + (ch/8)*128 + (gt%16)*8 + ch%8],  mt = gt/16.
#define TGT 32
template<typename T>
__device__ void num_body(const void* x, const bf16* __restrict__ conv,
                         const void* skw, const int* __restrict__ ia,
                         const int2* __restrict__ meta,
                         const int* __restrict__ off, const int* __restrict__ list,
                         bf16* __restrict__ xdf, float* __restrict__ st1){
    const int ch = threadIdx.x;
    const float sk = ld<T>(skw, ch);
    const int b = (blockIdx.x * TGT) / NTK;
    const long long choff = (long long)(ch >> 3)*128 + (ch & 7);
    float s = 0.f, q = 0.f;
    for (int r = 0; r < TGT; ++r){
        const int gt = blockIdx.x*TGT + r;
        const int gj = NTOK + gt;
        const int e  = off[gj];
        const int st = off[gj-1];
        float acc = 0.f, den = 0.f;
        for (int i = st; i < e; ++i){
            const int tok = list[i];                     // broadcast
            const int2 m = meta[tok];                    // broadcast
            const float wv = __int_as_float(m.y);
            const int j = ia[tok];                       // broadcast
            const float xv = ld<T>(x, ((long long)(b*NN + j))*CC + ch);
            const float cv = __bfloat162float(conv[((long long)(b*HW2 + m.x))*CC + ch]);
            acc += wv*(sk*xv + cv);
            den += wv;
        }
        const float v = acc / (den + 1e-6f);
        xdf[((long long)(gt >> 4))*4096 + (long long)(gt & 15)*8 + choff] = __float2bfloat16(v);
        s += v; q += v*v;
    }
    atomicAdd(&st1[ch], s);
    atomicAdd(&st1[CC + ch], q);
}
__global__ __launch_bounds__(256) void k_num(
        const void* x, const bf16* __restrict__ conv, const void* skw,
        const int* __restrict__ ia, const int2* __restrict__ meta,
        const int* __restrict__ off, const int* __restrict__ list,
        const float* __restrict__ flag,
        bf16* __restrict__ xdf, float* __restrict__ st1){
    if (flag[0] != 0.0f) num_body<bf16>(x, conv, skw, ia, meta, off, list, xdf, st1);
    else                 num_body<float>(x, conv, skw, ia, meta, off, list, xdf, st1);
}

// K6: finalize BN1 (a1, bshift) and bias2[o] = sum_c bshift[c]*w[o,c].
template<typename T>
__device__ void bn1_body(const float* __restrict__ st1, const void* g1, const void* b1,
                         const void* cw, float* __restrict__ ab1, float* __restrict__ bias2){
    __shared__ float sb[CC];
    const int tid = threadIdx.x;
    if (tid < CC){
        const float mean = st1[tid]/(float)RR;
        const float var  = st1[CC + tid]/(float)RR - mean*mean;
        const float a  = ld<T>(g1, tid) * rsqrtf(var + 1e-5f);
        const float bb = ld<T>(b1, tid) - mean*a;
        ab1[tid] = a; ab1[CC + tid] = bb;
        sb[tid] = bb;
    }
    __syncthreads();
    float acc = 0.f;
    for (int c = 0; c < CC; ++c) acc += sb[c]*ld<T>(cw, (long long)tid*CC + c);
    bias2[tid] = acc;
}
__global__ __launch_bounds__(512) void k_bn1(
        const float* __restrict__ st1, const void* g1, const void* b1, const void* cw,
        const float* __restrict__ flag, float* __restrict__ ab1, float* __restrict__ bias2){
    if (flag[0] != 0.0f) bn1_body<bf16>(st1, g1, b1, cw, ab1, bias2);
    else                 bn1_body<float>(st1, g1, b1, cw, ab1, bias2);
}

// K6b: wTf in MFMA-B fragment layout (bf16): for o,c:
//      wTf[(o/16)*4096 + (c/8)*128 + (o%16)*8 + c%8] = w[o][c]*a1[c]
template<typename T>
__device__ void wt_body(const void* cw, const float* __restrict__ ab1, bf16* __restrict__ wTf){
    const int c = blockIdx.x, o = threadIdx.x;
    const float v = ld<T>(cw, (long long)o*CC + c) * ab1[c];
    wTf[(((long long)(o >> 4)*32 + (c >> 3))*16 + (o & 15))*8 + (c & 7)] = __float2bfloat16(v);
}
__global__ __launch_bounds__(512) void k_wt(
        const void* cw, const float* __restrict__ ab1,
        const float* __restrict__ flag, bf16* __restrict__ wTf){
    if (flag[0] != 0.0f) wt_body<bf16>(cw, ab1, wTf);
    else                 wt_body<float>(cw, ab1, wTf);
}

// K7: MFMA GEMM. Block = 4 waves; wave = 16 rows x 128 cols.
//     2-D grid (384, 4): mb = blockIdx.x (384 NOT pow2 — do not mask!), nb = blockIdx.y.
__global__ __launch_bounds__(256) void k_gemm(
        const bf16* __restrict__ xdf, const bf16* __restrict__ wTf,
        const float* __restrict__ bias2, const float* __restrict__ flag,
        void* __restrict__ y, float* __restrict__ st2){
    __shared__ float ss[128], sq[128];
    const int tid = threadIdx.x;
    if (tid < 128){ ss[tid] = 0.f; sq[tid] = 0.f; }
    __syncthreads();
    const int wave = tid >> 6;
    const int lane = tid & 63;
    const int l16 = lane & 15;
    const int lq  = lane >> 4;
    const int mb = blockIdx.x;              // 0..383
    const int nb = blockIdx.y;              // 0..3
    const int mt = mb*4 + wave;             // m-tile (16 rows)
    const int n0t = nb*8;                   // first n-tile
    const short* ap = (const short*)xdf + ((long long)mt*32 + lq)*128 + (long long)l16*8;
    const short* bp = (const short*)wTf + ((long long)n0t*32 + lq)*128 + (long long)l16*8;
    f32x4 acc[8];
    #pragma unroll
    for (int nt = 0; nt < 8; ++nt) acc[nt] = (f32x4){0.f,0.f,0.f,0.f};
    #pragma unroll
    for (int kg0 = 0; kg0 < 8; ++kg0){
        const bf16x8 af = *((const bf16x8*)(ap + kg0*512));
        #pragma unroll
        for (int nt = 0; nt < 8; ++nt){
            const bf16x8 bfr = *((const bf16x8*)(bp + (long long)nt*4096 + kg0*512));
            acc[nt] = __builtin_amdgcn_mfma_f32_16x16x32_bf16(af, bfr, acc[nt], 0, 0, 0);
        }
    }
    const int row0 = mt*16 + lq*4;
    const bool isbf = (flag[0] != 0.0f);
    #pragma unroll
    for (int nt = 0; nt < 8; ++nt){
        const int col = nb*128 + nt*16 + l16;
        const float bz = bias2[col];
        float s = 0.f, q = 0.f;
        float v[4];
        #pragma unroll
        for (int r = 0; r < 4; ++r){
            v[r] = acc[nt][r] + bz;
            s += v[r]; q += v[r]*v[r];
        }
        if (isbf){
            bf16* yo = (bf16*)y;
            #pragma unroll
            for (int r = 0; r < 4; ++r)
                yo[(long long)(row0 + r)*CCO + col] = __float2bfloat16(v[r]);
        } else {
            float* yo = (float*)y;
            #pragma unroll
            for (int r = 0; r < 4; ++r)
                yo[(long long)(row0 + r)*CCO + col] = v[r];
        }
        // reduce over the 4 row-quads (lane bits 4,5) then one LDS atomic
        s += __shfl_xor(s, 16); s += __shfl_xor(s, 32);
        q += __shfl_xor(q, 16); q += __shfl_xor(q, 32);
        if (lq == 0){
            atomicAdd(&ss[nt*16 + l16], s);
            atomicAdd(&sq[nt*16 + l16], q);
        }
    }
    __syncthreads();
    if (tid < 128){
        atomicAdd(&st2[nb*128 + tid], ss[tid]);
        atomicAdd(&st2[CCO + nb*128 + tid], sq[tid]);
    }
}

// K8: finalize BN2 scale/shift.
template<typename T>
__device__ void bn2_body(const float* __restrict__ st2, const void* g2, const void* b2,
                         float* __restrict__ ab2){
    const int tid = threadIdx.x;
    const float mean = st2[tid]/(float)RR;
    const float var  = st2[CCO + tid]/(float)RR - mean*mean;
    const float a = ld<T>(g2, tid) * rsqrtf(var + 1e-5f);
    ab2[tid] = a;
    ab2[CCO + tid] = ld<T>(b2, tid) - mean*a;
}
__global__ __launch_bounds__(512) void k_bn2(
        const float* __restrict__ st2, const void* g2, const void* b2,
        const float* __restrict__ flag, float* __restrict__ ab2){
    if (flag[0] != 0.0f) bn2_body<bf16>(st2, g2, b2, ab2);
    else                 bn2_body<float>(st2, g2, b2, ab2);
}

// K9: in-place on d_out: out = relu(y*a2 + b2)
__global__ __launch_bounds__(256) void k_out(
        void* __restrict__ y, const float* __restrict__ ab2,
        const float* __restrict__ flag){
    const long long i = (long long)blockIdx.x*256 + threadIdx.x;
    const int o = (int)(i & (CCO-1));
    if (flag[0] != 0.0f){
        bf16* p = (bf16*)y;
        float v = __bfloat162float(p[i]);
        v = v*ab2[o] + ab2[CCO + o];
        p[i] = __float2bfloat16(fmaxf(v, 0.f));
    } else {
        float* p = (float*)y;
        float v = p[i]*ab2[o] + ab2[CCO + o];
        p[i] = fmaxf(v, 0.f);
    }
}

extern "C" void kernel_launch(void* const* d_in, const int* in_sizes, int n_in,
                              void* d_out, int out_size, void* d_ws, size_t ws_size,
                              hipStream_t stream){
    (void)in_sizes; (void)n_in; (void)out_size; (void)ws_size;
    const void* x   = d_in[0];
    const void* loc = d_in[1];
    const int*  ia  = (const int*)d_in[2];
    const int*  iat = (const int*)d_in[5];
    const void* wt  = d_in[6];
    const void* dww = d_in[9];
    const void* skw = d_in[10];
    const void* g1  = d_in[11];
    const void* b1  = d_in[12];
    const void* cw  = d_in[13];
    const void* g2  = d_in[14];
    const void* b2  = d_in[15];
    float* ws = (float*)d_ws;
    float* flag = ws + O_FLAG;
    int*  off  = (int*)(ws + O_OFF);
    int*  list = (int*)(ws + O_LIST);
    int*  aux  = (int*)(ws + O_AUX);
    int2* meta = (int2*)(ws + O_META);
    bf16* conv = (bf16*)(ws + O_CONV);
    bf16* xdf  = (bf16*)(ws + O_XD);
    bf16* wTf  = (bf16*)(ws + O_WT);

    hipMemsetAsync(ws + O_ST1, 0, (size_t)1536*4, stream);
    hipMemsetAsync(off, 0, (size_t)SCN*4, stream);

    k_flag<<<dim3(1), dim3(64), 0, stream>>>((const float*)loc, flag);

    k_meta<<<dim3(NTOK/256), dim3(256), 0, stream>>>(loc, iat, wt, flag, meta, off);

    k_scan1<<<dim3(SCB), dim3(1024), 0, stream>>>(off, aux);
    k_scan2<<<dim3(1), dim3(128), 0, stream>>>(aux);
    k_scan3<<<dim3(SCB), dim3(1024), 0, stream>>>(off, aux);

    k_fill<<<dim3(NTOK/256), dim3(256), 0, stream>>>(loc, ia, iat, flag, off, list);

    k_conv<<<dim3(BB*HW2), dim3(256), 0, stream>>>(x, dww, flag, off, list, conv);

    k_num<<<dim3(RR/TGT), dim3(256), 0, stream>>>(
        x, conv, skw, ia, meta, off, list, flag, xdf, ws + O_ST1);

    k_bn1<<<dim3(1), dim3(512), 0, stream>>>(
        ws + O_ST1, g1, b1, cw, flag, ws + O_AB1, ws + O_B2);

    k_wt<<<dim3(CC), dim3(512), 0, stream>>>(cw, ws + O_AB1, flag, wTf);

    k_gemm<<<dim3(384, 4), dim3(256), 0, stream>>>(
        xdf, wTf, ws + O_B2, flag, d_out, ws + O_ST2);

    k_bn2<<<dim3(1), dim3(512), 0, stream>>>(ws + O_ST2, g2, b2, flag, ws + O_AB2);

    k_out<<<dim3((RR*CCO)/256), dim3(256), 0, stream>>>(d_out, ws + O_AB2, flag);
}

// Round 6
// 423.871 us; speedup vs baseline: 1.7311x; 1.1195x over previous
//
#include <hip/hip_runtime.h>
#include <hip/hip_bf16.h>

using bf16 = __hip_bfloat16;
typedef __attribute__((ext_vector_type(8))) short bf16x8;
typedef __attribute__((ext_vector_type(4))) float f32x4;

#define BB   8
#define NN   12288
#define NTOK (BB*NN)      // 98304
#define NTK  3072
#define CC   256
#define CCO  512
#define HH   128
#define WWI  96
#define HWIN (HH*WWI)     // 12288
#define H2   64
#define W2   48
#define HW2  (H2*W2)      // 3072
#define RR   (BB*NTK)     // 24576

// ---- workspace layout (float-word offsets), end = 13233668 words = 52.93 MB
#define O_CONV  0LL          // conv bf16: 6291456 elems -> 3145728 words
#define O_XD    6291456LL    // xdf bf16 fragment layout: 6291456 elems -> 3145728 words
#define O_AUX   9437184LL    // 128 ints (scan block sums)
#define O_WT    12582912LL   // wTf bf16 fragment layout: 131072 elems -> 65536 words
#define O_ST1   12713984LL   // 512
#define O_ST2   12714496LL   // 1024 (contiguous with ST1)
#define O_AB1   12715520LL   // 512
#define O_B2    12716032LL   // 512
#define O_AB2   12716544LL   // 1024
#define O_FLAG  12717568LL   // 4
#define O_META  12717572LL   // 196608 (int2 per token {hw2, wv})
#define O_OFF   12914180LL   // 122880 ints: joint [cells(98304) | targets(24576)]
#define O_LIST  13037060LL   // 196608 ints: joint [listA | listB]
// end 13233668

__device__ __forceinline__ float cvt(float v){ return v; }
__device__ __forceinline__ float cvt(bf16 v){ return __bfloat162float(v); }
template<typename T>
__device__ __forceinline__ float ld(const void* p, long long i){
    return cvt(((const T*)p)[i]);
}
__device__ __forceinline__ float bfu(unsigned short u){
    return __uint_as_float((unsigned)u << 16);
}
__device__ __forceinline__ unsigned short ubf(float f){
    bf16 h = __float2bfloat16(f);
    return *(unsigned short*)&h;
}
// load 4 consecutive elements (first index i, i%4==0) as f32x4
template<typename T>
__device__ __forceinline__ f32x4 ld4(const void* p, long long i);
template<>
__device__ __forceinline__ f32x4 ld4<bf16>(const void* p, long long i){
    const ushort4 u = *(const ushort4*)((const unsigned short*)p + i);
    return (f32x4){bfu(u.x), bfu(u.y), bfu(u.z), bfu(u.w)};
}
template<>
__device__ __forceinline__ f32x4 ld4<float>(const void* p, long long i){
    const float4 v = *(const float4*)((const float*)p + i);
    return (f32x4){v.x, v.y, v.z, v.w};
}

// dtype detector: loc_orig ~ U(-1,1); f32 words all in [-1,1], bf16-reinterp huge.
__global__ void k_flag(const float* __restrict__ locf, float* __restrict__ flag){
    if (threadIdx.x == 0){
        int bad = 0;
        for (int i = 0; i < 64; ++i){
            const float v = locf[i];
            if (!(v >= -1.0f && v <= 1.0f)) bad = 1;
        }
        flag[0] = bad ? 1.0f : 0.0f;
    }
}

__device__ __forceinline__ int2 gidx2(float lx, float ly, int h, int w){
    lx = fminf(fmaxf(lx, -1.f), 1.f);
    ly = fminf(fmaxf(ly, -1.f), 1.f);
    int xi = (int)rintf(0.5f*(lx+1.f)*(float)w - 0.5f);
    int yi = (int)rintf(0.5f*(ly+1.f)*(float)h - 0.5f);
    xi = min(max(xi,0), w-1); yi = min(max(yi,0), h-1);
    return make_int2(xi, yi);
}

// K1: meta {hw2, wv} + joint histogram (cells then targets).
template<typename T>
__device__ void meta_body(const void* loc, const int* __restrict__ iat, const void* wt,
                          int2* __restrict__ meta, int* __restrict__ off){
    const int tok = blockIdx.x*256 + threadIdx.x;
    const int b = tok / NN;
    const float lx = ld<T>(loc, 2LL*tok);
    const float ly = ld<T>(loc, 2LL*tok + 1);
    const int2 g1 = gidx2(lx, ly, HH, WWI);
    const int2 g2 = gidx2(lx, ly, H2, W2);
    const float wv = ld<T>(wt, tok);
    int2 m; m.x = g2.x + g2.y*W2; m.y = __float_as_int(wv);
    meta[tok] = m;
    atomicAdd(&off[b*HWIN + g1.x + g1.y*WWI], 1);
    atomicAdd(&off[NTOK + b*NTK + iat[tok]], 1);
}
__global__ __launch_bounds__(256) void k_meta(
        const void* loc, const int* __restrict__ iat, const void* wt,
        const float* __restrict__ flag, int2* __restrict__ meta,
        int* __restrict__ off){
    if (flag[0] != 0.0f) meta_body<bf16>(loc, iat, wt, meta, off);
    else                 meta_body<float>(loc, iat, wt, meta, off);
}

// Scan over joint off[122880]: S1 per-block excl scan + totals, S2 scan totals, S3 add.
#define SCN  (NTOK + RR)     // 122880
#define SCB  120             // 120 blocks x 1024
__global__ __launch_bounds__(1024) void k_scan1(int* __restrict__ off, int* __restrict__ aux){
    __shared__ int sm[1024];
    const int tid = threadIdx.x;
    const int gid = blockIdx.x*1024 + tid;
    const int v = off[gid];
    sm[tid] = v;
    __syncthreads();
    for (int d = 1; d < 1024; d <<= 1){
        const int t = (tid >= d) ? sm[tid-d] : 0;
        __syncthreads();
        sm[tid] += t;
        __syncthreads();
    }
    off[gid] = sm[tid] - v;                    // exclusive within block
    if (tid == 1023) aux[blockIdx.x] = sm[1023];
}
__global__ __launch_bounds__(128) void k_scan2(int* __restrict__ aux){
    __shared__ int sm[128];
    const int tid = threadIdx.x;
    const int v = (tid < SCB) ? aux[tid] : 0;
    sm[tid] = v;
    __syncthreads();
    for (int d = 1; d < 128; d <<= 1){
        const int t = (tid >= d) ? sm[tid-d] : 0;
        __syncthreads();
        sm[tid] += t;
        __syncthreads();
    }
    if (tid < SCB) aux[tid] = sm[tid] - v;     // exclusive
}
__global__ __launch_bounds__(1024) void k_scan3(int* __restrict__ off, const int* __restrict__ aux){
    off[blockIdx.x*1024 + threadIdx.x] += aux[blockIdx.x];
}

// K3: fill joint CSR list. After this off holds inclusive ends.
template<typename T>
__device__ void fill_body(const void* loc, const int* __restrict__ ia,
                          const int* __restrict__ iat,
                          int* __restrict__ off, int* __restrict__ list){
    const int tok = blockIdx.x*256 + threadIdx.x;
    const int b = tok / NN;
    const float lx = ld<T>(loc, 2LL*tok);
    const float ly = ld<T>(loc, 2LL*tok + 1);
    const int2 g1 = gidx2(lx, ly, HH, WWI);
    const int pa = atomicAdd(&off[b*HWIN + g1.x + g1.y*WWI], 1);
    list[pa] = b*NN + ia[tok];
    const int pb = atomicAdd(&off[NTOK + b*NTK + iat[tok]], 1);
    list[pb] = tok;
}
__global__ __launch_bounds__(256) void k_fill(
        const void* loc, const int* __restrict__ ia, const int* __restrict__ iat,
        const float* __restrict__ flag,
        int* __restrict__ off, int* __restrict__ list){
    if (flag[0] != 0.0f) fill_body<bf16>(loc, ia, iat, off, list);
    else                 fill_body<float>(loc, ia, iat, off, list);
}

// K4: gather-conv, wave-per-output-cell, 4 ch/lane. Block = 4 waves = 4 cells.
template<typename T>
__device__ void conv_body(const void* x, const void* dww,
                          const int* __restrict__ off, const int* __restrict__ list,
                          bf16* __restrict__ conv){
    const int wave = threadIdx.x >> 6;
    const int lane = threadIdx.x & 63;
    const int ch0 = lane*4;
    const int cell = blockIdx.x*4 + wave;          // 0..24575
    const int b = cell / HW2;
    const int p = cell % HW2;
    const int oh = p / W2, ow = p % W2;
    float acc0 = 0.f, acc1 = 0.f, acc2 = 0.f, acc3 = 0.f;
    #pragma unroll
    for (int kh = 0; kh < 3; ++kh){
        const int ih = 2*oh - 1 + kh;
        if (ih < 0 || ih >= HH) continue;
        #pragma unroll
        for (int kw = 0; kw < 3; ++kw){
            const int iw = 2*ow - 1 + kw;
            if (iw < 0 || iw >= WWI) continue;
            const int g = b*HWIN + ih*WWI + iw;
            const int e = off[g];
            const int s = (g > 0) ? off[g-1] : 0;
            const int ln = e - s;
            if (ln == 0) continue;
            float s0=0.f, s1=0.f, s2=0.f, s3=0.f;
            for (int i = s; i < e; ++i){
                const int row = list[i];                       // broadcast
                const f32x4 xv = ld4<T>(x, (long long)row*CC + ch0);
                s0 += xv[0]; s1 += xv[1]; s2 += xv[2]; s3 += xv[3];
            }
            const float rl = 1.0f/((float)ln + 1e-6f);
            const int k = kh*3 + kw;
            acc0 += ld<T>(dww, (ch0  )*9 + k) * s0 * rl;
            acc1 += ld<T>(dww, (ch0+1)*9 + k) * s1 * rl;
            acc2 += ld<T>(dww, (ch0+2)*9 + k) * s2 * rl;
            acc3 += ld<T>(dww, (ch0+3)*9 + k) * s3 * rl;
        }
    }
    ushort4 o;
    o.x = ubf(acc0); o.y = ubf(acc1); o.z = ubf(acc2); o.w = ubf(acc3);
    *(ushort4*)((unsigned short*)conv + (long long)cell*CC + ch0) = o;
}
__global__ __launch_bounds__(256) void k_conv(
        const void* x, const void* dww, const float* __restrict__ flag,
        const int* __restrict__ off, const int* __restrict__ list,
        bf16* __restrict__ conv){
    if (flag[0] != 0.0f) conv_body<bf16>(x, dww, off, list, conv);
    else                 conv_body<float>(x, dww, off, list, conv);
}

// K5: per-target gather, wave-per-target (4 targets/wave serial), 4 ch/lane.
//     xd -> MFMA-A fragment layout bf16 + BN1 stats (LDS reduce, 1 atomic/ch/block).
#define TGW 4
template<typename T>
__device__ void num_body(const void* x, const bf16* __restrict__ conv,
                         const void* skw, const int* __restrict__ ia,
                         const int2* __restrict__ meta,
                         const int* __restrict__ off, const int* __restrict__ list,
                         bf16* __restrict__ xdf, float* __restrict__ st1){
    __shared__ float ss[CC], sq[CC];
    const int tid = threadIdx.x;
    ss[tid] = 0.f; sq[tid] = 0.f;
    __syncthreads();
    const int wave = tid >> 6;
    const int lane = tid & 63;
    const int ch0 = lane*4;
    const f32x4 sk = ld4<T>(skw, ch0);
    float sa0=0.f,sa1=0.f,sa2=0.f,sa3=0.f, qa0=0.f,qa1=0.f,qa2=0.f,qa3=0.f;
    const int W = blockIdx.x*4 + wave;             // global wave id, 0..6143
    for (int t = 0; t < TGW; ++t){
        const int gt = W*TGW + t;                  // target 0..24575
        const int b = gt / NTK;
        const int gj = NTOK + gt;
        const int e  = off[gj];
        const int s  = off[gj-1];
        float a0=0.f,a1=0.f,a2=0.f,a3=0.f, den=0.f;
        for (int i = s; i < e; ++i){
            const int tok = list[i];               // broadcast
            const int2 m = meta[tok];              // broadcast
            const float wv = __int_as_float(m.y);
            const int j = ia[tok];                 // broadcast
            const f32x4 xv = ld4<T>(x, ((long long)(b*NN + j))*CC + ch0);
            const f32x4 cv = ld4<bf16>(conv, ((long long)(b*HW2 + m.x))*CC + ch0);
            a0 += wv*(sk[0]*xv[0] + cv[0]);
            a1 += wv*(sk[1]*xv[1] + cv[1]);
            a2 += wv*(sk[2]*xv[2] + cv[2]);
            a3 += wv*(sk[3]*xv[3] + cv[3]);
            den += wv;
        }
        const float rl = 1.0f/(den + 1e-6f);
        const float v0 = a0*rl, v1 = a1*rl, v2 = a2*rl, v3 = a3*rl;
        ushort4 o; o.x = ubf(v0); o.y = ubf(v1); o.z = ubf(v2); o.w = ubf(v3);
        const long long bi = (long long)(gt >> 4)*4096 + (long long)(ch0 >> 3)*128
                           + (long long)(gt & 15)*8 + (ch0 & 7);
        *(ushort4*)((unsigned short*)xdf + bi) = o;
        sa0 += v0; sa1 += v1; sa2 += v2; sa3 += v3;
        qa0 += v0*v0; qa1 += v1*v1; qa2 += v2*v2; qa3 += v3*v3;
    }
    atomicAdd(&ss[ch0  ], sa0); atomicAdd(&sq[ch0  ], qa0);
    atomicAdd(&ss[ch0+1], sa1); atomicAdd(&sq[ch0+1], qa1);
    atomicAdd(&ss[ch0+2], sa2); atomicAdd(&sq[ch0+2], qa2);
    atomicAdd(&ss[ch0+3], sa3); atomicAdd(&sq[ch0+3], qa3);
    __syncthreads();
    atomicAdd(&st1[tid], ss[tid]);
    atomicAdd(&st1[CC + tid], sq[tid]);
}
__global__ __launch_bounds__(256) void k_num(
        const void* x, const bf16* __restrict__ conv, const void* skw,
        const int* __restrict__ ia, const int2* __restrict__ meta,
        const int* __restrict__ off, const int* __restrict__ list,
        const float* __restrict__ flag,
        bf16* __restrict__ xdf, float* __restrict__ st1){
    if (flag[0] != 0.0f) num_body<bf16>(x, conv, skw, ia, meta, off, list, xdf, st1);
    else                 num_body<float>(x, conv, skw, ia, meta, off, list, xdf, st1);
}

// K6: finalize BN1 (a1, bshift) and bias2[o] = sum_c bshift[c]*w[o,c].
template<typename T>
__device__ void bn1_body(const float* __restrict__ st1, const void* g1, const void* b1,
                         const void* cw, float* __restrict__ ab1, float* __restrict__ bias2){
    __shared__ float sb[CC];
    const int tid = threadIdx.x;
    if (tid < CC){
        const float mean = st1[tid]/(float)RR;
        const float var  = st1[CC + tid]/(float)RR - mean*mean;
        const float a  = ld<T>(g1, tid) * rsqrtf(var + 1e-5f);
        const float bb = ld<T>(b1, tid) - mean*a;
        ab1[tid] = a; ab1[CC + tid] = bb;
        sb[tid] = bb;
    }
    __syncthreads();
    float acc = 0.f;
    for (int c = 0; c < CC; ++c) acc += sb[c]*ld<T>(cw, (long long)tid*CC + c);
    bias2[tid] = acc;
}
__global__ __launch_bounds__(512) void k_bn1(
        const float* __restrict__ st1, const void* g1, const void* b1, const void* cw,
        const float* __restrict__ flag, float* __restrict__ ab1, float* __restrict__ bias2){
    if (flag[0] != 0.0f) bn1_body<bf16>(st1, g1, b1, cw, ab1, bias2);
    else                 bn1_body<float>(st1, g1, b1, cw, ab1, bias2);
}

// K6b: wTf in MFMA-B fragment layout (bf16)
template<typename T>
__device__ void wt_body(const void* cw, const float* __restrict__ ab1, bf16* __restrict__ wTf){
    const int c = blockIdx.x, o = threadIdx.x;
    const float v = ld<T>(cw, (long long)o*CC + c) * ab1[c];
    wTf[(((long long)(o >> 4)*32 + (c >> 3))*16 + (o & 15))*8 + (c & 7)] = __float2bfloat16(v);
}
__global__ __launch_bounds__(512) void k_wt(
        const void* cw, const float* __restrict__ ab1,
        const float* __restrict__ flag, bf16* __restrict__ wTf){
    if (flag[0] != 0.0f) wt_body<bf16>(cw, ab1, wTf);
    else                 wt_body<float>(cw, ab1, wTf);
}

// K7: MFMA GEMM. Block = 4 waves; wave = 16 rows x 128 cols.
//     2-D grid (384, 4): mb = blockIdx.x (384 NOT pow2 — do not mask!), nb = blockIdx.y.
__global__ __launch_bounds__(256) void k_gemm(
        const bf16* __restrict__ xdf, const bf16* __restrict__ wTf,
        const float* __restrict__ bias2, const float* __restrict__ flag,
        void* __restrict__ y, float* __restrict__ st2){
    __shared__ float ss[128], sq[128];
    const int tid = threadIdx.x;
    if (tid < 128){ ss[tid] = 0.f; sq[tid] = 0.f; }
    __syncthreads();
    const int wave = tid >> 6;
    const int lane = tid & 63;
    const int l16 = lane & 15;
    const int lq  = lane >> 4;
    const int mb = blockIdx.x;              // 0..383
    const int nb = blockIdx.y;              // 0..3
    const int mt = mb*4 + wave;             // m-tile (16 rows)
    const int n0t = nb*8;                   // first n-tile
    const short* ap = (const short*)xdf + ((long long)mt*32 + lq)*128 + (long long)l16*8;
    const short* bp = (const short*)wTf + ((long long)n0t*32 + lq)*128 + (long long)l16*8;
    f32x4 acc[8];
    #pragma unroll
    for (int nt = 0; nt < 8; ++nt) acc[nt] = (f32x4){0.f,0.f,0.f,0.f};
    #pragma unroll
    for (int kg0 = 0; kg0 < 8; ++kg0){
        const bf16x8 af = *((const bf16x8*)(ap + kg0*512));
        #pragma unroll
        for (int nt = 0; nt < 8; ++nt){
            const bf16x8 bfr = *((const bf16x8*)(bp + (long long)nt*4096 + kg0*512));
            acc[nt] = __builtin_amdgcn_mfma_f32_16x16x32_bf16(af, bfr, acc[nt], 0, 0, 0);
        }
    }
    const int row0 = mt*16 + lq*4;
    const bool isbf = (flag[0] != 0.0f);
    #pragma unroll
    for (int nt = 0; nt < 8; ++nt){
        const int col = nb*128 + nt*16 + l16;
        const float bz = bias2[col];
        float s = 0.f, q = 0.f;
        float v[4];
        #pragma unroll
        for (int r = 0; r < 4; ++r){
            v[r] = acc[nt][r] + bz;
            s += v[r]; q += v[r]*v[r];
        }
        if (isbf){
            bf16* yo = (bf16*)y;
            #pragma unroll
            for (int r = 0; r < 4; ++r)
                yo[(long long)(row0 + r)*CCO + col] = __float2bfloat16(v[r]);
        } else {
            float* yo = (float*)y;
            #pragma unroll
            for (int r = 0; r < 4; ++r)
                yo[(long long)(row0 + r)*CCO + col] = v[r];
        }
        s += __shfl_xor(s, 16); s += __shfl_xor(s, 32);
        q += __shfl_xor(q, 16); q += __shfl_xor(q, 32);
        if (lq == 0){
            atomicAdd(&ss[nt*16 + l16], s);
            atomicAdd(&sq[nt*16 + l16], q);
        }
    }
    __syncthreads();
    if (tid < 128){
        atomicAdd(&st2[nb*128 + tid], ss[tid]);
        atomicAdd(&st2[CCO + nb*128 + tid], sq[tid]);
    }
}

// K8: finalize BN2 scale/shift.
template<typename T>
__device__ void bn2_body(const float* __restrict__ st2, const void* g2, const void* b2,
                         float* __restrict__ ab2){
    const int tid = threadIdx.x;
    const float mean = st2[tid]/(float)RR;
    const float var  = st2[CCO + tid]/(float)RR - mean*mean;
    const float a = ld<T>(g2, tid) * rsqrtf(var + 1e-5f);
    ab2[tid] = a;
    ab2[CCO + tid] = ld<T>(b2, tid) - mean*a;
}
__global__ __launch_bounds__(512) void k_bn2(
        const float* __restrict__ st2, const void* g2, const void* b2,
        const float* __restrict__ flag, float* __restrict__ ab2){
    if (flag[0] != 0.0f) bn2_body<bf16>(st2, g2, b2, ab2);
    else                 bn2_body<float>(st2, g2, b2, ab2);
}

// K9: in-place on d_out: out = relu(y*a2 + b2), 4 elems/thread.
__global__ __launch_bounds__(256) void k_out(
        void* __restrict__ y, const float* __restrict__ ab2,
        const float* __restrict__ flag){
    const long long i0 = ((long long)blockIdx.x*256 + threadIdx.x)*4;
    const int o0 = (int)(i0 & (CCO-1));
    if (flag[0] != 0.0f){
        unsigned short* p = (unsigned short*)y;
        ushort4 u = *(ushort4*)(p + i0);
        float v0 = bfu(u.x)*ab2[o0  ] + ab2[CCO + o0  ];
        float v1 = bfu(u.y)*ab2[o0+1] + ab2[CCO + o0+1];
        float v2 = bfu(u.z)*ab2[o0+2] + ab2[CCO + o0+2];
        float v3 = bfu(u.w)*ab2[o0+3] + ab2[CCO + o0+3];
        u.x = ubf(fmaxf(v0,0.f)); u.y = ubf(fmaxf(v1,0.f));
        u.z = ubf(fmaxf(v2,0.f)); u.w = ubf(fmaxf(v3,0.f));
        *(ushort4*)(p + i0) = u;
    } else {
        float* p = (float*)y;
        float4 v = *(float4*)(p + i0);
        v.x = fmaxf(v.x*ab2[o0  ] + ab2[CCO + o0  ], 0.f);
        v.y = fmaxf(v.y*ab2[o0+1] + ab2[CCO + o0+1], 0.f);
        v.z = fmaxf(v.z*ab2[o0+2] + ab2[CCO + o0+2], 0.f);
        v.w = fmaxf(v.w*ab2[o0+3] + ab2[CCO + o0+3], 0.f);
        *(float4*)(p + i0) = v;
    }
}

extern "C" void kernel_launch(void* const* d_in, const int* in_sizes, int n_in,
                              void* d_out, int out_size, void* d_ws, size_t ws_size,
                              hipStream_t stream){
    (void)in_sizes; (void)n_in; (void)out_size; (void)ws_size;
    const void* x   = d_in[0];
    const void* loc = d_in[1];
    const int*  ia  = (const int*)d_in[2];
    const int*  iat = (const int*)d_in[5];
    const void* wt  = d_in[6];
    const void* dww = d_in[9];
    const void* skw = d_in[10];
    const void* g1  = d_in[11];
    const void* b1  = d_in[12];
    const void* cw  = d_in[13];
    const void* g2  = d_in[14];
    const void* b2  = d_in[15];
    float* ws = (float*)d_ws;
    float* flag = ws + O_FLAG;
    int*  off  = (int*)(ws + O_OFF);
    int*  list = (int*)(ws + O_LIST);
    int*  aux  = (int*)(ws + O_AUX);
    int2* meta = (int2*)(ws + O_META);
    bf16* conv = (bf16*)(ws + O_CONV);
    bf16* xdf  = (bf16*)(ws + O_XD);
    bf16* wTf  = (bf16*)(ws + O_WT);

    hipMemsetAsync(ws + O_ST1, 0, (size_t)1536*4, stream);
    hipMemsetAsync(off, 0, (size_t)SCN*4, stream);

    k_flag<<<dim3(1), dim3(64), 0, stream>>>((const float*)loc, flag);

    k_meta<<<dim3(NTOK/256), dim3(256), 0, stream>>>(loc, iat, wt, flag, meta, off);

    k_scan1<<<dim3(SCB), dim3(1024), 0, stream>>>(off, aux);
    k_scan2<<<dim3(1), dim3(128), 0, stream>>>(aux);
    k_scan3<<<dim3(SCB), dim3(1024), 0, stream>>>(off, aux);

    k_fill<<<dim3(NTOK/256), dim3(256), 0, stream>>>(loc, ia, iat, flag, off, list);

    k_conv<<<dim3(BB*HW2/4), dim3(256), 0, stream>>>(x, dww, flag, off, list, conv);

    k_num<<<dim3(RR/(4*TGW)), dim3(256), 0, stream>>>(
        x, conv, skw, ia, meta, off, list, flag, xdf, ws + O_ST1);

    k_bn1<<<dim3(1), dim3(512), 0, stream>>>(
        ws + O_ST1, g1, b1, cw, flag, ws + O_AB1, ws + O_B2);

    k_wt<<<dim3(CC), dim3(512), 0, stream>>>(cw, ws + O_AB1, flag, wTf);

    k_gemm<<<dim3(384, 4), dim3(256), 0, stream>>>(
        xdf, wTf, ws + O_B2, flag, d_out, ws + O_ST2);

    k_bn2<<<dim3(1), dim3(512), 0, stream>>>(ws + O_ST2, g2, b2, flag, ws + O_AB2);

    k_out<<<dim3((RR*CCO)/1024, 1), dim3(256), 0, stream>>>(d_out, ws + O_AB2, flag);
}